// Round 1
// baseline (7855.157 us; speedup 1.0000x reference)
//
#include <hip/hip_runtime.h>
#include <hip/hip_fp16.h>

typedef _Float16 f16x8 __attribute__((ext_vector_type(8)));
typedef float f32x4 __attribute__((ext_vector_type(4)));
typedef unsigned short u16x8 __attribute__((ext_vector_type(8)));
typedef unsigned short ushort_t;
typedef unsigned int uint32;

constexpr size_t BTH = 128ull * 1024ull * 512ull;  // 67108864

__device__ __forceinline__ ushort_t f2h(float f) {
  return __half_as_ushort(__float2half(f));
}

// ---- pre-pass: x fp32 [b][t][k] -> fp16 [t][b][k] ----
__global__ void cvt_xT(const float* __restrict__ x, ushort_t* __restrict__ xT) {
  int row = blockIdx.x * 4 + (threadIdx.x >> 6);   // row = b*1024 + t
  int lane = threadIdx.x & 63;
  int b = row >> 10, t = row & 1023;
  const float* src = x + (size_t)row * 512 + lane * 8;
  float4 f0 = *(const float4*)src;
  float4 f1 = *(const float4*)(src + 4);
  u16x8 u;
  u[0] = f2h(f0.x); u[1] = f2h(f0.y); u[2] = f2h(f0.z); u[3] = f2h(f0.w);
  u[4] = f2h(f1.x); u[5] = f2h(f1.y); u[6] = f2h(f1.z); u[7] = f2h(f1.w);
  *(u16x8*)(xT + ((size_t)t * 128 + b) * 512 + lane * 8) = u;
}

// ---- main persistent recurrence kernel ----
// 256 blocks x 256 threads. block(bid): rg = bid&7 (16 batch rows), cg = bid>>3 (16 h-cols).
// Wave w handles vcols w*16..w*16+15 where vcol v = 4*j + q  (j = local h-col, q = gate).
template<bool XPRE>
__global__ __launch_bounds__(256, 1)
void lstm_rec(const float* __restrict__ x,
              const ushort_t* __restrict__ xT,
              const float* __restrict__ h0,
              const float* __restrict__ c0,
              const float* __restrict__ Wi,
              const float* __restrict__ bi,
              const float* __restrict__ Wh,
              const float* __restrict__ bh,
              float* __restrict__ out,
              uint32* __restrict__ hbuf32,   // [2][128][256] u32 (=2 fp16 each)
              uint32* __restrict__ flags)    // [8][32]
{
  extern __shared__ char smem[];
  ushort_t* Wis = (ushort_t*)smem;                // [64][512] fp16, swizzled
  ushort_t* Whs = (ushort_t*)(smem + 65536);      // [64][512]
  ushort_t* hls = (ushort_t*)(smem + 131072);     // [16][512] fp16, swizzled
  float*    gst = (float*)(smem + 147456);        // 4 waves * 280 floats

  const int tid = threadIdx.x;
  const int lane = tid & 63;
  const int w = tid >> 6;
  const int l15 = lane & 15;
  const int hi = lane >> 4;
  const int bid = blockIdx.x;
  const int rg = bid & 7;
  const int cg = bid >> 3;
  const int rowbase = rg << 4;
  const int colbase = cg << 4;

  // ---------- weight preload: fp32 global -> fp16 LDS, [vcol][k] XOR-swizzled ----------
  {
    const int j4 = (tid & 3) << 2;       // 0,4,8,12
    const int q  = (tid >> 2) & 3;
    const int kb = tid >> 4;             // 0..15
    const int gc = (q << 9) + colbase + j4;
    for (int i = 0; i < 32; ++i) {
      int k = kb + (i << 4);
      float4 wi4 = *(const float4*)(Wi + (size_t)k * 2048 + gc);
      float4 wh4 = *(const float4*)(Wh + (size_t)k * 2048 + gc);
      #pragma unroll
      for (int m = 0; m < 4; ++m) {
        int v = ((j4 + m) << 2) + q;
        int idx = (v << 9) + ((((k >> 3) ^ (v & 7)) << 3) | (k & 7));
        Wis[idx] = f2h(((const float*)&wi4)[m]);
        Whs[idx] = f2h(((const float*)&wh4)[m]);
      }
    }
  }

  // bias for my vcol (MFMA D col = lane&15)
  const int myv = (w << 4) + l15;
  const int mygc = ((myv & 3) << 9) + colbase + (myv >> 2);
  const float biasv = bi[mygc] + bh[mygc];

  // elementwise-phase mapping: row = lane&15, local j = lane>>4
  const int myrow = rowbase + l15;
  const int mycol = colbase + (w << 2) + hi;
  float c = c0[myrow * 512 + mycol];

  // h0 init -> hbuf[0] (packed u32, agent-scope so it lands at LLC)
  if (tid < 128) {
    int r = tid >> 3, c2 = tid & 7;
    int grow = rowbase + r;
    int gcol = colbase + (c2 << 1);
    uint32 lo  = f2h(h0[grow * 512 + gcol]);
    uint32 hi2 = f2h(h0[grow * 512 + gcol + 1]);
    __hip_atomic_store(hbuf32 + grow * 256 + (gcol >> 1), lo | (hi2 << 16),
                       __ATOMIC_RELAXED, __HIP_MEMORY_SCOPE_AGENT);
  }
  __syncthreads();   // drains vmcnt -> h0 slice at LLC before flag
  uint32* const myflag = flags + (rg << 5) + cg;
  if (tid == 0)
    __hip_atomic_store(myflag, 1u, __ATOMIC_RELAXED, __HIP_MEMORY_SCOPE_AGENT);

  const size_t xT_lane = (size_t)(rowbase + l15) * 512 + (hi << 3);
  const float* xf_lane = x + ((size_t)(rowbase + l15) * 1024) * 512 + (hi << 3);
  uint32* const fl = flags + (rg << 5) + (lane & 31);
  const int rsw = l15 & 7;
  const int vsw = myv & 7;
  const ushort_t* wiB = Wis + (myv << 9);
  const ushort_t* whB = Whs + (myv << 9);
  const ushort_t* hrow = hls + (l15 << 9);

  for (int t = 0; t < 1024; ++t) {
    // ---- wait for all 32 producers of this rowgroup ----
    if (w == 0) {
      const uint32 tgt = (uint32)(t + 1);
      while (true) {
        uint32 f = __hip_atomic_load(fl, __ATOMIC_RELAXED, __HIP_MEMORY_SCOPE_AGENT);
        if (__all((int)(f >= tgt))) break;
      }
    }
    __syncthreads();

    // ---- stage h (16 rows x 512) LLC -> LDS, XOR-swizzled ----
    {
      uint32* hsrc = hbuf32 + (t & 1) * 32768 + (rowbase << 8);
      #pragma unroll
      for (int i = 0; i < 16; ++i) {
        int flat = (i << 8) + tid;
        uint32 v = __hip_atomic_load(hsrc + flat, __ATOMIC_RELAXED, __HIP_MEMORY_SCOPE_AGENT);
        int r = flat >> 8, c32 = flat & 255;
        ((uint32*)hls)[(r << 8) + (((c32 >> 2) ^ (r & 7)) << 2) + (c32 & 3)] = v;
      }
    }
    __syncthreads();

    // ---- gates = bias + x(t)*Wi + h*Wh  (fp16 MFMA, fp32 accum) ----
    f32x4 aI0 = {0.f, 0.f, 0.f, 0.f}, aI1 = {0.f, 0.f, 0.f, 0.f};
    f32x4 aH0 = {biasv, biasv, biasv, biasv}, aH1 = {0.f, 0.f, 0.f, 0.f};
    const ushort_t* xrow = XPRE ? xT + (((size_t)t) << 16) + xT_lane : nullptr;
    const float* xrf = XPRE ? nullptr : xf_lane + (((size_t)t) << 9);
    #pragma unroll
    for (int kk = 0; kk < 16; ++kk) {
      const int k0 = kk << 5;
      f16x8 ah = *(const f16x8*)(hrow + ((((kk << 2) + hi) ^ rsw) << 3));
      f16x8 ax;
      if (XPRE) {
        ax = *(const f16x8*)(xrow + k0);
      } else {
        float4 xa = *(const float4*)(xrf + k0);
        float4 xb = *(const float4*)(xrf + k0 + 4);
        ax[0] = (_Float16)xa.x; ax[1] = (_Float16)xa.y;
        ax[2] = (_Float16)xa.z; ax[3] = (_Float16)xa.w;
        ax[4] = (_Float16)xb.x; ax[5] = (_Float16)xb.y;
        ax[6] = (_Float16)xb.z; ax[7] = (_Float16)xb.w;
      }
      const int bofs = (((kk << 2) + hi) ^ vsw) << 3;
      f16x8 bI = *(const f16x8*)(wiB + bofs);
      f16x8 bH = *(const f16x8*)(whB + bofs);
      if (kk & 1) {
        aI1 = __builtin_amdgcn_mfma_f32_16x16x32_f16(ax, bI, aI1, 0, 0, 0);
        aH1 = __builtin_amdgcn_mfma_f32_16x16x32_f16(ah, bH, aH1, 0, 0, 0);
      } else {
        aI0 = __builtin_amdgcn_mfma_f32_16x16x32_f16(ax, bI, aI0, 0, 0, 0);
        aH0 = __builtin_amdgcn_mfma_f32_16x16x32_f16(ah, bH, aH0, 0, 0, 0);
      }
    }
    f32x4 acc = (aI0 + aI1) + (aH0 + aH1);

    // ---- gate exchange: [vc][row] in per-wave LDS slab (stride 17 vs conflicts) ----
    {
      float* gp = gst + w * 280 + l15 * 17 + (hi << 2);
      gp[0] = acc[0]; gp[1] = acc[1]; gp[2] = acc[2]; gp[3] = acc[3];
    }
    __syncthreads();
    const float* gq = gst + w * 280 + (hi << 2) * 17 + l15;
    const float gI = gq[0], gF = gq[17], gG = gq[34], gO = gq[51];

    const float ig = 1.f / (1.f + __expf(-gI));
    const float fg = 1.f / (1.f + __expf(-gF));
    const float gg = 1.f - 2.f / (1.f + __expf(2.f * gG));
    const float og = 1.f / (1.f + __expf(-gO));
    c = fg * c + ig * gg;
    const float hv = og * (1.f - 2.f / (1.f + __expf(2.f * c)));

    out[((size_t)myrow * 1024 + (size_t)t) * 512 + mycol] = hv;

    // pack 2 adjacent cols (partner lane = lane^16) -> one u32 agent store
    ushort_t hb = f2h(hv);
    uint32 pp = (uint32)__shfl_xor((int)(uint32)hb, 16);
    if ((hi & 1) == 0) {
      uint32 packed = ((pp & 0xffffu) << 16) | (uint32)hb;
      __hip_atomic_store(hbuf32 + ((t + 1) & 1) * 32768 + (myrow << 8) + (mycol >> 1),
                         packed, __ATOMIC_RELAXED, __HIP_MEMORY_SCOPE_AGENT);
    }
    if (t == 1023) {
      out[BTH + (size_t)myrow * 512 + mycol] = hv;             // hy
      out[BTH + 65536 + (size_t)myrow * 512 + mycol] = c;      // cy
    }
    __syncthreads();   // drains vmcnt(0): h stores acked at LLC before flag bump
    if (tid == 0)
      __hip_atomic_store(myflag, (uint32)(t + 2), __ATOMIC_RELAXED, __HIP_MEMORY_SCOPE_AGENT);
  }
}

extern "C" void kernel_launch(void* const* d_in, const int* in_sizes, int n_in,
                              void* d_out, int out_size, void* d_ws, size_t ws_size,
                              hipStream_t stream) {
  const float* x  = (const float*)d_in[0];
  const float* h0 = (const float*)d_in[1];
  const float* c0 = (const float*)d_in[2];
  // d_in[3] = ctx (unused by reference forward)
  const float* Wi = (const float*)d_in[4];
  const float* bi = (const float*)d_in[5];
  const float* Wh = (const float*)d_in[6];
  const float* bh = (const float*)d_in[7];
  float* out = (float*)d_out;

  char* ws = (char*)d_ws;
  uint32* flags = (uint32*)ws;                       // 1 KB used
  uint32* hbuf32 = (uint32*)(ws + 4096);             // 256 KB
  ushort_t* xT = (ushort_t*)(ws + (1u << 20));       // 128 MB (optional)
  const size_t need_xpre = (1ull << 20) + 134217728ull;
  const bool xpre = ws_size >= need_xpre;

  hipMemsetAsync(ws, 0, 4096, stream);               // zero sync flags every call

  if (xpre) {
    cvt_xT<<<dim3(32768), dim3(256), 0, stream>>>(x, xT);
  }

  const int LDS_BYTES = 147456 + 4480;               // 151,936 B
  if (xpre) {
    hipFuncSetAttribute((const void*)lstm_rec<true>,
                        hipFuncAttributeMaxDynamicSharedMemorySize, LDS_BYTES);
    void* args[] = {(void*)&x, (void*)&xT, (void*)&h0, (void*)&c0, (void*)&Wi,
                    (void*)&bi, (void*)&Wh, (void*)&bh, (void*)&out,
                    (void*)&hbuf32, (void*)&flags};
    hipLaunchCooperativeKernel((const void*)lstm_rec<true>, dim3(256), dim3(256),
                               args, LDS_BYTES, stream);
  } else {
    hipFuncSetAttribute((const void*)lstm_rec<false>,
                        hipFuncAttributeMaxDynamicSharedMemorySize, LDS_BYTES);
    void* args[] = {(void*)&x, (void*)&xT, (void*)&h0, (void*)&c0, (void*)&Wi,
                    (void*)&bi, (void*)&Wh, (void*)&bh, (void*)&out,
                    (void*)&hbuf32, (void*)&flags};
    hipLaunchCooperativeKernel((const void*)lstm_rec<false>, dim3(256), dim3(256),
                               args, LDS_BYTES, stream);
  }
}

// Round 2
// 7319.827 us; speedup vs baseline: 1.0731x; 1.0731x over previous
//
#include <hip/hip_runtime.h>
#include <hip/hip_fp16.h>

typedef _Float16 f16x8 __attribute__((ext_vector_type(8)));
typedef float f32x4 __attribute__((ext_vector_type(4)));
typedef unsigned short u16x8 __attribute__((ext_vector_type(8)));
typedef unsigned short ushort_t;
typedef unsigned int uint32;
typedef uint32 u32x4 __attribute__((ext_vector_type(4)));

constexpr size_t BTH = 128ull * 1024ull * 512ull;  // 67108864

__device__ __forceinline__ ushort_t f2h(float f) {
  return __half_as_ushort(__float2half(f));
}

// ---- tagged-word communication primitives (fast = sc0 only, stays in local XCD L2;
//      slow = sc0 sc1, coherent at LLC for cross-XCD groups) ----
__device__ __forceinline__ u32x4 ld4t(const uint32* p, bool fast) {
  u32x4 r;
  if (fast) asm volatile("global_load_dwordx4 %0, %1, off sc0" : "=v"(r) : "v"(p));
  else      asm volatile("global_load_dwordx4 %0, %1, off sc0 sc1" : "=v"(r) : "v"(p));
  return r;
}
__device__ __forceinline__ void st1t(uint32* p, uint32 v, bool fast) {
  if (fast) asm volatile("global_store_dword %0, %1, off sc0" :: "v"(p), "v"(v) : "memory");
  else      asm volatile("global_store_dword %0, %1, off sc0 sc1" :: "v"(p), "v"(v) : "memory");
}
__device__ __forceinline__ void waitvm0() {
  asm volatile("s_waitcnt vmcnt(0)" ::: "memory");
  __builtin_amdgcn_sched_barrier(0);
}

// ---- pre-pass: x fp32 [b][t][k] -> fp16 [t][b][k] ----
__global__ void cvt_xT(const float* __restrict__ x, ushort_t* __restrict__ xT) {
  int row = blockIdx.x * 4 + (threadIdx.x >> 6);   // row = b*1024 + t
  int lane = threadIdx.x & 63;
  int b = row >> 10, t = row & 1023;
  const float* src = x + (size_t)row * 512 + lane * 8;
  float4 f0 = *(const float4*)src;
  float4 f1 = *(const float4*)(src + 4);
  u16x8 u;
  u[0] = f2h(f0.x); u[1] = f2h(f0.y); u[2] = f2h(f0.z); u[3] = f2h(f0.w);
  u[4] = f2h(f1.x); u[5] = f2h(f1.y); u[6] = f2h(f1.z); u[7] = f2h(f1.w);
  *(u16x8*)(xT + ((size_t)t * 128 + b) * 512 + lane * 8) = u;
}

// ---- main persistent recurrence kernel ----
// 256 blocks x 256 threads. Rowgroup (16 batch rows) x 32 colgroup blocks (16 h-cols each).
// Rowgroup/colgroup assignment is DYNAMIC: if blocks are balanced 32-per-XCD (read via
// HW_REG_XCC_ID), rowgroup = physical XCD and h exchange stays in the local L2 (fast path).
template<bool XPRE>
__global__ __launch_bounds__(256, 1)
void lstm_rec(const float* __restrict__ x,
              const ushort_t* __restrict__ xT,
              const float* __restrict__ h0,
              const float* __restrict__ c0,
              const float* __restrict__ Wi,
              const float* __restrict__ bi,
              const float* __restrict__ Wh,
              const float* __restrict__ bh,
              float* __restrict__ out,
              uint32* __restrict__ hbuf,    // [2][8][16][512] tagged u32
              uint32* __restrict__ ctrl)    // [0..7] per-xcd cnt, [8] arrival, [9] barrier
{
  extern __shared__ char smem[];
  ushort_t* Wis = (ushort_t*)smem;                // [64][512] fp16, swizzled
  ushort_t* Whs = (ushort_t*)(smem + 65536);      // [64][512]
  ushort_t* hls = (ushort_t*)(smem + 131072);     // [16][512] fp16, swizzled
  float*    gst = (float*)(smem + 147456);        // 4 waves * 280 floats
  __shared__ int s_rg, s_cg, s_fast;

  const int tid = threadIdx.x;
  const int lane = tid & 63;
  const int w = tid >> 6;
  const int l15 = lane & 15;
  const int hi = lane >> 4;

  // ---------- registration: discover physical XCD, form rowgroups ----------
  if (tid == 0) {
    uint32 xcc;
    asm volatile("s_getreg_b32 %0, hwreg(HW_REG_XCC_ID)" : "=s"(xcc));
    xcc &= 7u;
    uint32 rin = __hip_atomic_fetch_add(&ctrl[xcc], 1u, __ATOMIC_RELAXED, __HIP_MEMORY_SCOPE_AGENT);
    uint32 ar  = __hip_atomic_fetch_add(&ctrl[8],   1u, __ATOMIC_RELAXED, __HIP_MEMORY_SCOPE_AGENT);
    __hip_atomic_fetch_add(&ctrl[9], 1u, __ATOMIC_ACQ_REL, __HIP_MEMORY_SCOPE_AGENT);
    while (__hip_atomic_load(&ctrl[9], __ATOMIC_ACQUIRE, __HIP_MEMORY_SCOPE_AGENT) < 256u)
      __builtin_amdgcn_s_sleep(2);
    bool bal = true;
    for (int i = 0; i < 8; ++i)
      bal &= (__hip_atomic_load(&ctrl[i], __ATOMIC_RELAXED, __HIP_MEMORY_SCOPE_AGENT) == 32u);
    if (bal) { s_rg = (int)xcc;      s_cg = (int)rin;      s_fast = 1; }
    else     { s_rg = (int)(ar >> 5); s_cg = (int)(ar & 31); s_fast = 0; }
  }
  __syncthreads();
  const int rg = s_rg, cg = s_cg;
  const bool fast = (s_fast != 0);
  const int rowbase = rg << 4;
  const int colbase = cg << 4;

  // elementwise-phase mapping: row = lane&15, local j = lane>>4
  const int myrow = rowbase + l15;
  const int mycol = colbase + (w << 2) + hi;

  // ---------- h0 -> tagged words (tag 1, parity 0) as early as possible ----------
  uint32* wr0 = hbuf + ((size_t)rg << 13) + (l15 << 9) + mycol;        // parity 0 slab
  uint32* wr1 = hbuf + ((size_t)(8 + rg) << 13) + (l15 << 9) + mycol;  // parity 1 slab
  st1t(wr0, (1u << 16) | (uint32)f2h(h0[myrow * 512 + mycol]), fast);

  // ---------- weight preload: fp32 global -> fp16 LDS, [vcol][k] XOR-swizzled ----------
  {
    const int j4 = (tid & 3) << 2;       // 0,4,8,12
    const int q  = (tid >> 2) & 3;
    const int kb = tid >> 4;             // 0..15
    const int gc = (q << 9) + colbase + j4;
    for (int i = 0; i < 32; ++i) {
      int k = kb + (i << 4);
      float4 wi4 = *(const float4*)(Wi + (size_t)k * 2048 + gc);
      float4 wh4 = *(const float4*)(Wh + (size_t)k * 2048 + gc);
      #pragma unroll
      for (int m = 0; m < 4; ++m) {
        int v2 = ((j4 + m) << 2) + q;
        int idx = (v2 << 9) + ((((k >> 3) ^ (v2 & 7)) << 3) | (k & 7));
        Wis[idx] = f2h(((const float*)&wi4)[m]);
        Whs[idx] = f2h(((const float*)&wh4)[m]);
      }
    }
  }

  // bias for my vcol (MFMA D col = lane&15); vcol v = 4*j + gate
  const int myv = (w << 4) + l15;
  const int mygc = ((myv & 3) << 9) + colbase + (myv >> 2);
  const float biasv = bi[mygc] + bh[mygc];
  float c = c0[myrow * 512 + mycol];

  const size_t xT_lane = (size_t)(rowbase + l15) * 512 + (hi << 3);
  const float* xf_lane = x + ((size_t)(rowbase + l15) * 1024) * 512 + (hi << 3);
  const int rsw = l15 & 7;
  const int vsw = myv & 7;
  const ushort_t* wiB = Wis + (myv << 9);
  const ushort_t* whB = Whs + (myv << 9);
  const ushort_t* hrow = hls + (l15 << 9);

  __syncthreads();   // weights visible in LDS

  // x * Wi + bias for step t -> f32x4 (16 MFMAs, runs OFF the h critical path)
  auto x_gemm = [&](int t) -> f32x4 {
    f32x4 a0 = {biasv, biasv, biasv, biasv}, a1 = {0.f, 0.f, 0.f, 0.f};
    if (XPRE) {
      const ushort_t* xrow = xT + (((size_t)t) << 16) + xT_lane;
      #pragma unroll
      for (int kk = 0; kk < 16; ++kk) {
        f16x8 ax = *(const f16x8*)(xrow + (kk << 5));
        f16x8 bI = *(const f16x8*)(wiB + ((((kk << 2) + hi) ^ vsw) << 3));
        if (kk & 1) a1 = __builtin_amdgcn_mfma_f32_16x16x32_f16(ax, bI, a1, 0, 0, 0);
        else        a0 = __builtin_amdgcn_mfma_f32_16x16x32_f16(ax, bI, a0, 0, 0, 0);
      }
    } else {
      const float* xrf = xf_lane + (((size_t)t) << 9);
      #pragma unroll
      for (int kk = 0; kk < 16; ++kk) {
        const int k0 = kk << 5;
        float4 xa = *(const float4*)(xrf + k0);
        float4 xb = *(const float4*)(xrf + k0 + 4);
        f16x8 ax;
        ax[0] = (_Float16)xa.x; ax[1] = (_Float16)xa.y;
        ax[2] = (_Float16)xa.z; ax[3] = (_Float16)xa.w;
        ax[4] = (_Float16)xb.x; ax[5] = (_Float16)xb.y;
        ax[6] = (_Float16)xb.z; ax[7] = (_Float16)xb.w;
        f16x8 bI = *(const f16x8*)(wiB + ((((kk << 2) + hi) ^ vsw) << 3));
        if (kk & 1) a1 = __builtin_amdgcn_mfma_f32_16x16x32_f16(ax, bI, a1, 0, 0, 0);
        else        a0 = __builtin_amdgcn_mfma_f32_16x16x32_f16(ax, bI, a0, 0, 0, 0);
      }
    }
    return a0 + a1;
  };

  f32x4 axb = x_gemm(0);

  const uint32* rd0 = hbuf + ((size_t)rg << 13) + (tid << 2);
  const uint32* rd1 = hbuf + ((size_t)(8 + rg) << 13) + (tid << 2);

  for (int t = 0; t < 1024; ++t) {
    // ---- poll + stage h(t): tagged words, parity t&1, expected tag t+1 ----
    {
      const uint32* base = (t & 1) ? rd1 : rd0;
      const uint32 etag = (uint32)(t + 1);
      u32x4 v[8];
      #pragma unroll
      for (int j = 0; j < 8; ++j) v[j] = ld4t(base + (j << 10), fast);
      waitvm0();
      #pragma unroll
      for (int j = 0; j < 8; ++j) {
        u32x4 vv = v[j];
        while (((vv[0] >> 16) != etag) | ((vv[1] >> 16) != etag) |
               ((vv[2] >> 16) != etag) | ((vv[3] >> 16) != etag)) {
          __builtin_amdgcn_s_sleep(1);
          vv = ld4t(base + (j << 10), fast);
          waitvm0();
        }
        const int w0 = (j << 10) + (tid << 2);     // word idx: row = w0>>9, col = w0&511
        const int r = w0 >> 9;
        const int c32 = (w0 & 511) >> 1;           // even
        uint32 p0 = (vv[0] & 0xffffu) | (vv[1] << 16);
        uint32 p1 = (vv[2] & 0xffffu) | (vv[3] << 16);
        uint32* dst = (uint32*)hls + (r << 8) + (((c32 >> 2) ^ (r & 7)) << 2) + (c32 & 3);
        dst[0] = p0; dst[1] = p1;
      }
    }
    __syncthreads();

    // ---- gates = axb + h*Wh (16 fp16 MFMAs, fp32 accum) ----
    f32x4 aH0 = axb, aH1 = {0.f, 0.f, 0.f, 0.f};
    #pragma unroll
    for (int kk = 0; kk < 16; ++kk) {
      f16x8 ah = *(const f16x8*)(hrow + ((((kk << 2) + hi) ^ rsw) << 3));
      f16x8 bH = *(const f16x8*)(whB + ((((kk << 2) + hi) ^ vsw) << 3));
      if (kk & 1) aH1 = __builtin_amdgcn_mfma_f32_16x16x32_f16(ah, bH, aH1, 0, 0, 0);
      else        aH0 = __builtin_amdgcn_mfma_f32_16x16x32_f16(ah, bH, aH0, 0, 0, 0);
    }
    f32x4 acc = aH0 + aH1;
    __syncthreads();   // hls reads done -> next iteration's staging may overwrite

    // ---- gate exchange: per-WAVE LDS slab (in-order DS, no barrier needed) ----
    {
      float* gp = gst + w * 280 + l15 * 17 + (hi << 2);
      gp[0] = acc[0]; gp[1] = acc[1]; gp[2] = acc[2]; gp[3] = acc[3];
    }
    const float* gq = gst + w * 280 + (hi << 2) * 17 + l15;
    const float gI = gq[0], gF = gq[17], gG = gq[34], gO = gq[51];

    const float ig = 1.f / (1.f + __expf(-gI));
    const float fg = 1.f / (1.f + __expf(-gF));
    const float gg = 1.f - 2.f / (1.f + __expf(2.f * gG));
    const float og = 1.f / (1.f + __expf(-gO));
    c = fg * c + ig * gg;
    const float hv = og * (1.f - 2.f / (1.f + __expf(2.f * c)));

    // ---- produce h(t+1) FIRST (critical for peers), then out, then next x GEMM ----
    if (t < 1023) {
      uint32 word = ((uint32)(t + 2) << 16) | (uint32)f2h(hv);
      st1t((t & 1) ? wr0 : wr1, word, fast);
    }
    out[((size_t)myrow << 19) + ((size_t)t << 9) + mycol] = hv;
    if (t == 1023) {
      out[BTH + (size_t)myrow * 512 + mycol] = hv;            // hy
      out[BTH + 65536 + (size_t)myrow * 512 + mycol] = c;     // cy
    }
    if (t < 1023) axb = x_gemm(t + 1);
  }
}

extern "C" void kernel_launch(void* const* d_in, const int* in_sizes, int n_in,
                              void* d_out, int out_size, void* d_ws, size_t ws_size,
                              hipStream_t stream) {
  const float* x  = (const float*)d_in[0];
  const float* h0 = (const float*)d_in[1];
  const float* c0 = (const float*)d_in[2];
  // d_in[3] = ctx (unused by reference forward)
  const float* Wi = (const float*)d_in[4];
  const float* bi = (const float*)d_in[5];
  const float* Wh = (const float*)d_in[6];
  const float* bh = (const float*)d_in[7];
  float* out = (float*)d_out;

  char* ws = (char*)d_ws;
  uint32* ctrl = (uint32*)ws;                        // 64 B used
  uint32* hbuf = (uint32*)(ws + 4096);               // 512 KB tagged h
  ushort_t* xT = (ushort_t*)(ws + (1u << 20));       // 128 MB (optional)
  const size_t need_xpre = (1ull << 20) + 134217728ull;
  const bool xpre = ws_size >= need_xpre;

  // zero ctrl + hbuf tags every launch (tags must not survive across replays)
  hipMemsetAsync(ws, 0, 4096 + 524288, stream);

  if (xpre) {
    cvt_xT<<<dim3(32768), dim3(256), 0, stream>>>(x, xT);
  }

  const int LDS_BYTES = 147456 + 4480;               // 151,936 B
  if (xpre) {
    hipFuncSetAttribute((const void*)lstm_rec<true>,
                        hipFuncAttributeMaxDynamicSharedMemorySize, LDS_BYTES);
    void* args[] = {(void*)&x, (void*)&xT, (void*)&h0, (void*)&c0, (void*)&Wi,
                    (void*)&bi, (void*)&Wh, (void*)&bh, (void*)&out,
                    (void*)&hbuf, (void*)&ctrl};
    hipLaunchCooperativeKernel((const void*)lstm_rec<true>, dim3(256), dim3(256),
                               args, LDS_BYTES, stream);
  } else {
    hipFuncSetAttribute((const void*)lstm_rec<false>,
                        hipFuncAttributeMaxDynamicSharedMemorySize, LDS_BYTES);
    void* args[] = {(void*)&x, (void*)&xT, (void*)&h0, (void*)&c0, (void*)&Wi,
                    (void*)&bi, (void*)&Wh, (void*)&bh, (void*)&out,
                    (void*)&hbuf, (void*)&ctrl};
    hipLaunchCooperativeKernel((const void*)lstm_rec<false>, dim3(256), dim3(256),
                               args, LDS_BYTES, stream);
  }
}